// Round 12
// baseline (281.568 us; speedup 1.0000x reference)
//
#include <hip/hip_runtime.h>

typedef _Float16 f16;
typedef _Float16 f16x8 __attribute__((ext_vector_type(8)));
typedef _Float16 f16x4 __attribute__((ext_vector_type(4)));
typedef float    f32x4 __attribute__((ext_vector_type(4)));
typedef unsigned int u32t;

#define AS1 __attribute__((address_space(1)))
#define AS3 __attribute__((address_space(3)))

static __device__ __forceinline__ void gload_lds16(const void* g, void* l) {
  __builtin_amdgcn_global_load_lds((const AS1 u32t*)g, (AS3 u32t*)l, 16, 0, 0);
}

static __device__ __forceinline__ f16x8 zero8() {
  f16x8 z;
#pragma unroll
  for (int j = 0; j < 8; ++j) z[j] = (f16)0;
  return z;
}

// ------------- fused prep: W transposes + x convert in ONE launch -------------
__global__ void k_prep(const float* __restrict__ x,
                       const float* __restrict__ Wqkv,
                       const float* __restrict__ Wproj,
                       f16* __restrict__ X16, f16* __restrict__ WQT,
                       f16* __restrict__ WPT)
{
  __shared__ float T[32][33];
  const int bid = blockIdx.x;
  if (bid < 11200) {
    const float* W; f16* Wt; int N; int b2;
    if (bid < 4800) { W = Wqkv;  Wt = WQT; N = 3840; b2 = bid; }
    else            { W = Wproj; Wt = WPT; N = 5120; b2 = bid - 4800; }
    int bk = b2 % 40, bn = b2 / 40;
    int k0 = bk * 32, n0 = bn * 32;
    int r = threadIdx.x >> 5, c = threadIdx.x & 31;
#pragma unroll
    for (int i = 0; i < 4; ++i)
      T[r + i * 8][c] = W[(size_t)(k0 + r + i * 8) * N + n0 + c];
    __syncthreads();
#pragma unroll
    for (int i = 0; i < 4; ++i)
      Wt[(size_t)(n0 + r + i * 8) * 1280 + k0 + c] = (f16)T[c][r + i * 8];
  } else {
    const int n4 = 8192 * 1280 / 4;
    for (int i = (bid - 11200) * 256 + threadIdx.x; i < n4; i += 2048 * 256) {
      float4 v = ((const float4*)x)[i];
      f16x4 o;
      o[0] = (f16)v.x; o[1] = (f16)v.y; o[2] = (f16)v.z; o[3] = (f16)v.w;
      ((f16x4*)X16)[i] = o;
    }
  }
}

// ======= 256x256 GEMM, BK=64, 4-phase/tile counted-vmcnt (gemm1: ~57us deduced) =======
template<int NCOLS, bool F16OUT>
__global__ __launch_bounds__(512, 1)
void gemm_nt256(const f16* __restrict__ A, const f16* __restrict__ Bt,
                const float* __restrict__ bias, void* __restrict__ Cout)
{
  __shared__ __align__(16) char lds[131072];
  const int tid = threadIdx.x;
  const int wave = tid >> 6, lane = tid & 63;
  const int rl = lane & 15, g = lane >> 4;
  const int wm = wave >> 2, wn = wave & 3;

  constexpr int NBN = NCOLS / 256;
  constexpr int NWG = 32 * NBN;
  const int bid = blockIdx.x;
  const int wgid = (bid & 7) * (NWG / 8) + (bid >> 3);   // XCD swizzle (NWG%8==0)
  const int bm = wgid / NBN, bn = wgid % NBN;
  const long row0 = (long)bm * 256, col0 = (long)bn * 256;

  const int subA = wave * 8 + (lane >> 3);                    // 0..63
  const int cpA  = (((lane & 7) ^ (subA & 7)) << 4);
  const char* gAt = (const char*)A + (row0 + subA) * 2560 + cpA;
  const int subB = (wave & 3) * 8 + (lane >> 3);              // 0..31
  const int cpB  = (((lane & 7) ^ (subB & 7)) << 4);
  const char* gBt = (const char*)Bt + (col0 + (wave >> 2) * 64 + subB) * 2560 + cpB;
  char* const dA = lds + wave * 1024;
  char* const dB = lds + 65536 + wave * 1024;

  auto STA = [&](int mh, int buf, int kb) {
#pragma unroll
    for (int l = 0; l < 2; ++l)
      gload_lds16(gAt + mh * (64 * 2560) + l * (128 * 2560) + kb,
                  dA + buf * 32768 + mh * 16384 + l * 8192);
  };
  auto STB = [&](int nh, int buf, int kb) {
#pragma unroll
    for (int l = 0; l < 2; ++l)
      gload_lds16(gBt + nh * (32 * 2560) + l * (128 * 2560) + kb,
                  dB + buf * 32768 + nh * 16384 + l * 8192);
  };

  const int swz0 = ((0 + g) ^ (rl & 7)) << 4;
  const int swz1 = ((4 + g) ^ (rl & 7)) << 4;
  const int aro = wm * 8192 + rl * 128;
  const int bro = 65536 + wn * 4096 + rl * 128;

  auto LDA = [&](f16x8 (&af)[8], int buf, int mh) {
#pragma unroll
    for (int m = 0; m < 4; ++m) {
      const char* p = lds + buf * 32768 + mh * 16384 + aro + m * 2048;
      af[m * 2 + 0] = *(const f16x8*)(p + swz0);
      af[m * 2 + 1] = *(const f16x8*)(p + swz1);
    }
  };
  auto LDB = [&](f16x8 (&bf)[4], int buf, int nh) {
#pragma unroll
    for (int n = 0; n < 2; ++n) {
      const char* p = lds + buf * 32768 + nh * 16384 + bro + n * 2048;
      bf[n * 2 + 0] = *(const f16x8*)(p + swz0);
      bf[n * 2 + 1] = *(const f16x8*)(p + swz1);
    }
  };

  f32x4 acc[8][4];
#pragma unroll
  for (int m = 0; m < 8; ++m)
#pragma unroll
    for (int n = 0; n < 4; ++n) acc[m][n] = (f32x4){0.f, 0.f, 0.f, 0.f};

  auto MM = [&](int mh, int nh, const f16x8 (&af)[8], const f16x8 (&bf)[4]) {
    __builtin_amdgcn_s_setprio(1);
#pragma unroll
    for (int m = 0; m < 4; ++m)
#pragma unroll
      for (int n = 0; n < 2; ++n)
#pragma unroll
        for (int kk = 0; kk < 2; ++kk)
          acc[mh * 4 + m][nh * 2 + n] = __builtin_amdgcn_mfma_f32_16x16x32_f16(
              af[m * 2 + kk], bf[n * 2 + kk], acc[mh * 4 + m][nh * 2 + n], 0, 0, 0);
    __builtin_amdgcn_s_setprio(0);
  };

#define BAR()   do { __builtin_amdgcn_s_barrier(); asm volatile("" ::: "memory"); } while (0)
#define WLGKM() asm volatile("s_waitcnt lgkmcnt(0)" ::: "memory")
#define WVM(N)  asm volatile("s_waitcnt vmcnt(" #N ")" ::: "memory")

  auto TILE = [&](int buf, int kbB1, int kbN, int mode) {
    f16x8 af[8], bf0[4], bf1[4];
    LDA(af, buf, 0); LDB(bf0, buf, 0);
    if (mode <= 1) STB(1, buf ^ 1, kbB1);
    BAR(); WLGKM(); MM(0, 0, af, bf0); BAR();
    LDB(bf1, buf, 1);
    if (mode == 0) STA(0, buf, kbN);
    BAR(); WLGKM(); MM(0, 1, af, bf1); BAR();
    LDA(af, buf, 1);
    if (mode == 0) STB(0, buf, kbN);
    BAR(); WLGKM(); MM(1, 1, af, bf1); BAR();
    if (mode == 0) STA(1, buf, kbN);
    if (mode == 0) { WVM(6); } else if (mode == 1) { WVM(0); }
    BAR(); MM(1, 0, af, bf0);
    if (mode != 2) BAR();
  };

  STA(0, 0, 0); STB(0, 0, 0); STA(1, 0, 0); STB(1, 0, 0);
  STA(0, 1, 128); STB(0, 1, 128); STA(1, 1, 128);
  WVM(6); BAR();

#pragma unroll 1
  for (int it = 0; it < 9; ++it) {
    const int kb = it * 256;
    TILE(0, kb + 128, kb + 256, 0);
    TILE(1, kb + 256, kb + 384, 0);
  }
  TILE(0, 2432, 0, 1);
  TILE(1, 0, 0, 2);

#undef BAR
#undef WLGKM
#undef WVM

#pragma unroll
  for (int m = 0; m < 8; ++m) {
#pragma unroll
    for (int n = 0; n < 4; ++n) {
      long c = col0 + wn * 64 + n * 16 + rl;
      float bv = bias[c];
#pragma unroll
      for (int r = 0; r < 4; ++r) {
        long rr = row0 + wm * 128 + m * 16 + g * 4 + r;
        float v = acc[m][n][r] + bv;
        if (F16OUT) ((f16*)Cout)[rr * NCOLS + c] = (f16)v;
        else        ((float*)Cout)[rr * NCOLS + c] = v;
      }
    }
  }
}

// ======= 128x128 GEMM (R6 body, 951 TF measured); bm_base M-split for profiling =======
template<int NCOLS>
__global__ __launch_bounds__(256, 4)
void gemm_nt128(const f16* __restrict__ A, const f16* __restrict__ Bt,
                const float* __restrict__ bias, float* __restrict__ Cout, int bm_base)
{
  __shared__ __align__(16) char lds[32768];
  f16* const sA = (f16*)lds;
  f16* const sB = (f16*)(lds + 16384);
  const int tid = threadIdx.x;
  const int wave = tid >> 6, lane = tid & 63;
  constexpr int NBN = NCOLS / 128;
  const int bm = bm_base + blockIdx.x / NBN, bn = blockIdx.x % NBN;
  const long row0 = (long)bm * 128, col0 = (long)bn * 128;

  f32x4 acc[4][4];
#pragma unroll
  for (int i = 0; i < 4; ++i)
#pragma unroll
    for (int j = 0; j < 4; ++j) acc[i][j] = (f32x4){0.f, 0.f, 0.f, 0.f};

  const int wr = (wave >> 1) * 64, wc = (wave & 1) * 64;

  int segr[4], segoff[4];
#pragma unroll
  for (int i = 0; i < 4; ++i) {
    int o = (wave * 4 + i) * 1024 + lane * 16;
    int r = o >> 7, cb = o & 127;
    segr[i] = r;
    segoff[i] = cb ^ ((r & 7) << 4);
  }

  const char* Ab = (const char*)A;
  const char* Bb = (const char*)Bt;

  for (int kt = 0; kt < 20; ++kt) {
    __syncthreads();
#pragma unroll
    for (int i = 0; i < 4; ++i) {
      const char* ga = Ab + ((row0 + segr[i]) * 1280 + kt * 64) * 2 + segoff[i];
      gload_lds16(ga, (char*)sA + (wave * 4 + i) * 1024);
      const char* gb = Bb + ((col0 + segr[i]) * 1280 + kt * 64) * 2 + segoff[i];
      gload_lds16(gb, (char*)sB + (wave * 4 + i) * 1024);
    }
    __syncthreads();

#pragma unroll
    for (int kk = 0; kk < 2; ++kk) {
      const int rl = lane & 15, g = lane >> 4, x7 = lane & 7;
      const int ph = (kk * 4 + g) ^ x7;
      f16x8 af[4], bf[4];
#pragma unroll
      for (int mt = 0; mt < 4; ++mt)
        af[mt] = *(const f16x8*)(sA + (wr + mt * 16 + rl) * 64 + ph * 8);
#pragma unroll
      for (int nt = 0; nt < 4; ++nt)
        bf[nt] = *(const f16x8*)(sB + (wc + nt * 16 + rl) * 64 + ph * 8);
#pragma unroll
      for (int mt = 0; mt < 4; ++mt)
#pragma unroll
        for (int nt = 0; nt < 4; ++nt)
          acc[mt][nt] = __builtin_amdgcn_mfma_f32_16x16x32_f16(af[mt], bf[nt], acc[mt][nt], 0, 0, 0);
    }
  }

  const int rl = lane & 15, g = lane >> 4;
#pragma unroll
  for (int mt = 0; mt < 4; ++mt) {
#pragma unroll
    for (int nt = 0; nt < 4; ++nt) {
      long c = col0 + wc + nt * 16 + rl;
      float bv = bias[c];
#pragma unroll
      for (int r = 0; r < 4; ++r) {
        long rr = row0 + wr + mt * 16 + g * 4 + r;
        Cout[rr * NCOLS + c] = acc[mt][nt][r] + bv;
      }
    }
  }
}

// ---------------- V transpose: qkv v-part -> vt[b*16+h][80][2048] ----------------
__global__ void k_vt(const f16* __restrict__ qkv, f16* __restrict__ vt) {
  __shared__ __align__(16) f16 T[128 * 136];
  int bid = blockIdx.x;              // 64 bh * 16 s-chunks
  int sc16 = bid & 15, bh = bid >> 4;
  int b = bh >> 4, h = bh & 15;
  int s0 = sc16 * 128;
  int t = threadIdx.x;
#pragma unroll
  for (int i = 0; i < 5; ++i) {
    int cid = i * 256 + t;           // 1280 = 128 s * 10 chunks
    int s = cid / 10, c = cid % 10;
    const f16* g = qkv + (size_t)((s0 + s) * 4 + b) * 3840 + 2560 + h * 80 + c * 8;
    f16x8 v = *(const f16x8*)g;
    int phys = c ^ ((s >> 3) & 7);
    *(f16x8*)(T + s * 136 + phys * 8) = v;
  }
  __syncthreads();
#pragma unroll
  for (int i = 0; i < 5; ++i) {
    int oid = i * 256 + t;           // 1280 = 80 hd * 16 s-subchunks
    int sc8 = oid & 15, hd = oid >> 4;
    f16x8 o;
#pragma unroll
    for (int j = 0; j < 8; ++j) {
      int row = sc8 * 8 + j;
      int phys = (hd >> 3) ^ (sc8 & 7);
      o[j] = T[row * 136 + phys * 8 + (hd & 7)];
    }
    *(f16x8*)(vt + (size_t)(bh * 80 + hd) * 2048 + s0 + sc8 * 8) = o;
  }
}

// ---------------- windowed attention (qc-merged) ----------------
__global__ __launch_bounds__(512, 2)
void k_attn(const f16* __restrict__ qkv, const f16* __restrict__ vt,
            f16* __restrict__ ctx)
{
  __shared__ __align__(16) f16 sK[256 * 104];
  __shared__ __align__(16) f16 sV[80 * 264];
  __shared__ __align__(16) f16 sP[256 * 72];

  const int bid = blockIdx.x;                   // 512
  const int seg = bid & 7, h = (bid >> 3) & 15, b = bid >> 7;
  const int t = threadIdx.x;
  const int wave = t >> 6, lane = t & 63;
  const int s_key0 = seg * 256;

#pragma unroll
  for (int i = 0; i < 5; ++i) {
    int cid = i * 512 + t;
    int key = cid / 10, c = cid % 10;
    const f16* g = qkv + (size_t)((s_key0 + key) * 4 + b) * 3840 + 1280 + h * 80 + c * 8;
    *(f16x8*)(sK + key * 104 + c * 8) = *(const f16x8*)g;
  }
  {
    int key = t >> 1, c = t & 1;
    *(f16x8*)(sK + key * 104 + 80 + c * 8) = zero8();
  }
#pragma unroll
  for (int i = 0; i < 5; ++i) {
    int cid = i * 512 + t;
    int hd = cid >> 5, c = cid & 31;
    const f16* g = vt + (size_t)((b * 16 + h) * 80 + hd) * 2048 + s_key0 + c * 8;
    *(f16x8*)(sV + hd * 264 + c * 8) = *(const f16x8*)g;
  }

  const int q0 = s_key0 + wave * 32;
  const int rl = lane & 15, g = lane >> 4;
  f16x8 qfl[3], qfh[3];
  {
    const f16* gl = qkv + (size_t)((q0 + rl) * 4 + b) * 3840 + h * 80;
    const f16* gh = qkv + (size_t)((q0 + 16 + rl) * 4 + b) * 3840 + h * 80;
    qfl[0] = *(const f16x8*)(gl + g * 8);
    qfh[0] = *(const f16x8*)(gh + g * 8);
    qfl[1] = *(const f16x8*)(gl + 32 + g * 8);
    qfh[1] = *(const f16x8*)(gh + 32 + g * 8);
    if (g < 2) { qfl[2] = *(const f16x8*)(gl + 64 + g * 8); qfh[2] = *(const f16x8*)(gh + 64 + g * 8); }
    else       { qfl[2] = zero8(); qfh[2] = zero8(); }
  }
  __syncthreads();

  f32x4 scl[16], sch[16];
#pragma unroll
  for (int nt = 0; nt < 16; ++nt) { scl[nt] = (f32x4){0.f,0.f,0.f,0.f}; sch[nt] = (f32x4){0.f,0.f,0.f,0.f}; }
#pragma unroll
  for (int nt = 0; nt < 16; ++nt) {
#pragma unroll
    for (int kk = 0; kk < 3; ++kk) {
      f16x8 bf = *(const f16x8*)(sK + (nt * 16 + rl) * 104 + kk * 32 + g * 8);
      scl[nt] = __builtin_amdgcn_mfma_f32_16x16x32_f16(qfl[kk], bf, scl[nt], 0, 0, 0);
      sch[nt] = __builtin_amdgcn_mfma_f32_16x16x32_f16(qfh[kk], bf, sch[nt], 0, 0, 0);
    }
  }

  const float scale = 0.11180339887498949f;
  float invl[4], invh[4];
#pragma unroll
  for (int r = 0; r < 4; ++r) {
    float ml = -1e30f, mh = -1e30f;
#pragma unroll
    for (int nt = 0; nt < 16; ++nt) { ml = fmaxf(ml, scl[nt][r]); mh = fmaxf(mh, sch[nt][r]); }
#pragma unroll
    for (int off = 8; off >= 1; off >>= 1) { ml = fmaxf(ml, __shfl_xor(ml, off)); mh = fmaxf(mh, __shfl_xor(mh, off)); }
    ml *= scale; mh *= scale;
    float suml = 0.f, sumh = 0.f;
#pragma unroll
    for (int nt = 0; nt < 16; ++nt) {
      float pl = __expf(scl[nt][r] * scale - ml);
      float ph = __expf(sch[nt][r] * scale - mh);
      scl[nt][r] = pl; sch[nt][r] = ph;
      suml += pl; sumh += ph;
    }
#pragma unroll
    for (int off = 8; off >= 1; off >>= 1) { suml += __shfl_xor(suml, off); sumh += __shfl_xor(sumh, off); }
    invl[r] = 1.0f / suml; invh[r] = 1.0f / sumh;
  }

  f32x4 ol[5], oh[5];
#pragma unroll
  for (int nt = 0; nt < 5; ++nt) { ol[nt] = (f32x4){0.f,0.f,0.f,0.f}; oh[nt] = (f32x4){0.f,0.f,0.f,0.f}; }
  const int prow0 = wave * 32;
  for (int ch = 0; ch < 4; ++ch) {
#pragma unroll
    for (int f = 0; f < 4; ++f) {
      int nt = ch * 4 + f;
#pragma unroll
      for (int r = 0; r < 4; ++r) {
        sP[(prow0 + g * 4 + r) * 72 + f * 16 + rl]      = (f16)scl[nt][r];
        sP[(prow0 + 16 + g * 4 + r) * 72 + f * 16 + rl] = (f16)sch[nt][r];
      }
    }
#pragma unroll
    for (int kk = 0; kk < 2; ++kk) {
      f16x8 pal = *(const f16x8*)(sP + (prow0 + rl) * 72 + kk * 32 + g * 8);
      f16x8 pah = *(const f16x8*)(sP + (prow0 + 16 + rl) * 72 + kk * 32 + g * 8);
#pragma unroll
      for (int nt = 0; nt < 5; ++nt) {
        f16x8 vb = *(const f16x8*)(sV + (nt * 16 + rl) * 264 + ch * 64 + kk * 32 + g * 8);
        ol[nt] = __builtin_amdgcn_mfma_f32_16x16x32_f16(pal, vb, ol[nt], 0, 0, 0);
        oh[nt] = __builtin_amdgcn_mfma_f32_16x16x32_f16(pah, vb, oh[nt], 0, 0, 0);
      }
    }
  }

#pragma unroll
  for (int nt = 0; nt < 5; ++nt) {
    int hd = nt * 16 + rl;
#pragma unroll
    for (int r = 0; r < 4; ++r) {
      long qrl = q0 + g * 4 + r;
      ctx[(qrl * 4 + b) * 1280 + h * 80 + hd] = (f16)(ol[nt][r] * invl[r]);
      long qrh = q0 + 16 + g * 4 + r;
      ctx[(qrh * 4 + b) * 1280 + h * 80 + hd] = (f16)(oh[nt][r] * invh[r]);
    }
  }
}

extern "C" void kernel_launch(void* const* d_in, const int* in_sizes, int n_in,
                              void* d_out, int out_size, void* d_ws, size_t ws_size,
                              hipStream_t stream)
{
  const float* x     = (const float*)d_in[0];
  const float* Wqkv  = (const float*)d_in[1];
  const float* bqkv  = (const float*)d_in[2];
  const float* Wproj = (const float*)d_in[3];
  const float* bproj = (const float*)d_in[4];

  char* ws = (char*)d_ws;
  f16* X16   = (f16*)(ws);                 // 20,971,520 B (reused as CTX16 after gemm1)
  f16* WQT   = (f16*)(ws + 20971520);      //  9,830,400 B
  f16* WPT   = (f16*)(ws + 30801920);      // 13,107,200 B
  f16* QKV16 = (f16*)(ws + 43909120);      // 62,914,560 B
  f16* VT    = (f16*)(ws + 106823680);     // 20,971,520 B  (total 127,795,200 B)
  f16* CTX16 = X16;                        // x dead after gemm1

  k_prep<<<13248, 256, 0, stream>>>(x, Wqkv, Wproj, X16, WQT, WPT);
  gemm_nt256<3840, true><<<480, 512, 0, stream>>>(X16, WQT, bqkv, QKV16);
  k_vt<<<1024, 256, 0, stream>>>(QKV16, VT);
  k_attn<<<512, 512, 0, stream>>>(QKV16, VT, CTX16);
  // gemm2 M-split x3 (~38us each): makes gemm1-256 the longest dispatch so its
  // replays fill rocprof top-5 (direct counters at last). Steady-state cost ~0.
  gemm_nt128<5120><<<22 * 40, 256, 0, stream>>>(CTX16, WPT, bproj, (float*)d_out, 0);
  gemm_nt128<5120><<<21 * 40, 256, 0, stream>>>(CTX16, WPT, bproj, (float*)d_out, 22);
  gemm_nt128<5120><<<21 * 40, 256, 0, stream>>>(CTX16, WPT, bproj, (float*)d_out, 43);
}

// Round 13
// 263.166 us; speedup vs baseline: 1.0699x; 1.0699x over previous
//
#include <hip/hip_runtime.h>

typedef _Float16 f16;
typedef _Float16 f16x8 __attribute__((ext_vector_type(8)));
typedef _Float16 f16x4 __attribute__((ext_vector_type(4)));
typedef float    f32x4 __attribute__((ext_vector_type(4)));
typedef unsigned int u32t;

#define AS1 __attribute__((address_space(1)))
#define AS3 __attribute__((address_space(3)))

static __device__ __forceinline__ void gload_lds16(const void* g, void* l) {
  __builtin_amdgcn_global_load_lds((const AS1 u32t*)g, (AS3 u32t*)l, 16, 0, 0);
}

static __device__ __forceinline__ f16x8 zero8() {
  f16x8 z;
#pragma unroll
  for (int j = 0; j < 8; ++j) z[j] = (f16)0;
  return z;
}

// ------------- fused prep: W transposes + x convert in ONE launch -------------
__global__ void k_prep(const float* __restrict__ x,
                       const float* __restrict__ Wqkv,
                       const float* __restrict__ Wproj,
                       f16* __restrict__ X16, f16* __restrict__ WQT,
                       f16* __restrict__ WPT)
{
  __shared__ float T[32][33];
  const int bid = blockIdx.x;
  if (bid < 11200) {
    const float* W; f16* Wt; int N; int b2;
    if (bid < 4800) { W = Wqkv;  Wt = WQT; N = 3840; b2 = bid; }
    else            { W = Wproj; Wt = WPT; N = 5120; b2 = bid - 4800; }
    int bk = b2 % 40, bn = b2 / 40;
    int k0 = bk * 32, n0 = bn * 32;
    int r = threadIdx.x >> 5, c = threadIdx.x & 31;
#pragma unroll
    for (int i = 0; i < 4; ++i)
      T[r + i * 8][c] = W[(size_t)(k0 + r + i * 8) * N + n0 + c];
    __syncthreads();
#pragma unroll
    for (int i = 0; i < 4; ++i)
      Wt[(size_t)(n0 + r + i * 8) * 1280 + k0 + c] = (f16)T[c][r + i * 8];
  } else {
    const int n4 = 8192 * 1280 / 4;
    for (int i = (bid - 11200) * 256 + threadIdx.x; i < n4; i += 2048 * 256) {
      float4 v = ((const float4*)x)[i];
      f16x4 o;
      o[0] = (f16)v.x; o[1] = (f16)v.y; o[2] = (f16)v.z; o[3] = (f16)v.w;
      ((f16x4*)X16)[i] = o;
    }
  }
}

// ======= 256x256 GEMM, BK=64, 4-phase/tile counted-vmcnt (gemm1: 97.7us MEASURED) =======
template<int NCOLS, bool F16OUT>
__global__ __launch_bounds__(512, 1)
void gemm_nt256(const f16* __restrict__ A, const f16* __restrict__ Bt,
                const float* __restrict__ bias, void* __restrict__ Cout)
{
  __shared__ __align__(16) char lds[131072];
  const int tid = threadIdx.x;
  const int wave = tid >> 6, lane = tid & 63;
  const int rl = lane & 15, g = lane >> 4;
  const int wm = wave >> 2, wn = wave & 3;

  constexpr int NBN = NCOLS / 256;
  constexpr int NWG = 32 * NBN;
  const int bid = blockIdx.x;
  const int wgid = (bid & 7) * (NWG / 8) + (bid >> 3);   // XCD swizzle (NWG%8==0)
  const int bm = wgid / NBN, bn = wgid % NBN;
  const long row0 = (long)bm * 256, col0 = (long)bn * 256;

  const int subA = wave * 8 + (lane >> 3);                    // 0..63
  const int cpA  = (((lane & 7) ^ (subA & 7)) << 4);
  const char* gAt = (const char*)A + (row0 + subA) * 2560 + cpA;
  const int subB = (wave & 3) * 8 + (lane >> 3);              // 0..31
  const int cpB  = (((lane & 7) ^ (subB & 7)) << 4);
  const char* gBt = (const char*)Bt + (col0 + (wave >> 2) * 64 + subB) * 2560 + cpB;
  char* const dA = lds + wave * 1024;
  char* const dB = lds + 65536 + wave * 1024;

  auto STA = [&](int mh, int buf, int kb) {
#pragma unroll
    for (int l = 0; l < 2; ++l)
      gload_lds16(gAt + mh * (64 * 2560) + l * (128 * 2560) + kb,
                  dA + buf * 32768 + mh * 16384 + l * 8192);
  };
  auto STB = [&](int nh, int buf, int kb) {
#pragma unroll
    for (int l = 0; l < 2; ++l)
      gload_lds16(gBt + nh * (32 * 2560) + l * (128 * 2560) + kb,
                  dB + buf * 32768 + nh * 16384 + l * 8192);
  };

  const int swz0 = ((0 + g) ^ (rl & 7)) << 4;
  const int swz1 = ((4 + g) ^ (rl & 7)) << 4;
  const int aro = wm * 8192 + rl * 128;
  const int bro = 65536 + wn * 4096 + rl * 128;

  auto LDA = [&](f16x8 (&af)[8], int buf, int mh) {
#pragma unroll
    for (int m = 0; m < 4; ++m) {
      const char* p = lds + buf * 32768 + mh * 16384 + aro + m * 2048;
      af[m * 2 + 0] = *(const f16x8*)(p + swz0);
      af[m * 2 + 1] = *(const f16x8*)(p + swz1);
    }
  };
  auto LDB = [&](f16x8 (&bf)[4], int buf, int nh) {
#pragma unroll
    for (int n = 0; n < 2; ++n) {
      const char* p = lds + buf * 32768 + nh * 16384 + bro + n * 2048;
      bf[n * 2 + 0] = *(const f16x8*)(p + swz0);
      bf[n * 2 + 1] = *(const f16x8*)(p + swz1);
    }
  };

  f32x4 acc[8][4];
#pragma unroll
  for (int m = 0; m < 8; ++m)
#pragma unroll
    for (int n = 0; n < 4; ++n) acc[m][n] = (f32x4){0.f, 0.f, 0.f, 0.f};

  auto MM = [&](int mh, int nh, const f16x8 (&af)[8], const f16x8 (&bf)[4]) {
    __builtin_amdgcn_s_setprio(1);
#pragma unroll
    for (int m = 0; m < 4; ++m)
#pragma unroll
      for (int n = 0; n < 2; ++n)
#pragma unroll
        for (int kk = 0; kk < 2; ++kk)
          acc[mh * 4 + m][nh * 2 + n] = __builtin_amdgcn_mfma_f32_16x16x32_f16(
              af[m * 2 + kk], bf[n * 2 + kk], acc[mh * 4 + m][nh * 2 + n], 0, 0, 0);
    __builtin_amdgcn_s_setprio(0);
  };

#define BAR()   do { __builtin_amdgcn_s_barrier(); asm volatile("" ::: "memory"); } while (0)
#define WLGKM() asm volatile("s_waitcnt lgkmcnt(0)" ::: "memory")
#define WVM(N)  asm volatile("s_waitcnt vmcnt(" #N ")" ::: "memory")

  auto TILE = [&](int buf, int kbB1, int kbN, int mode) {
    f16x8 af[8], bf0[4], bf1[4];
    LDA(af, buf, 0); LDB(bf0, buf, 0);
    if (mode <= 1) STB(1, buf ^ 1, kbB1);
    BAR(); WLGKM(); MM(0, 0, af, bf0); BAR();
    LDB(bf1, buf, 1);
    if (mode == 0) STA(0, buf, kbN);
    BAR(); WLGKM(); MM(0, 1, af, bf1); BAR();
    LDA(af, buf, 1);
    if (mode == 0) STB(0, buf, kbN);
    BAR(); WLGKM(); MM(1, 1, af, bf1); BAR();
    if (mode == 0) STA(1, buf, kbN);
    if (mode == 0) { WVM(6); } else if (mode == 1) { WVM(0); }
    BAR(); MM(1, 0, af, bf0);
    if (mode != 2) BAR();
  };

  STA(0, 0, 0); STB(0, 0, 0); STA(1, 0, 0); STB(1, 0, 0);
  STA(0, 1, 128); STB(0, 1, 128); STA(1, 1, 128);
  WVM(6); BAR();

#pragma unroll 1
  for (int it = 0; it < 9; ++it) {
    const int kb = it * 256;
    TILE(0, kb + 128, kb + 256, 0);
    TILE(1, kb + 256, kb + 384, 0);
  }
  TILE(0, 2432, 0, 1);
  TILE(1, 0, 0, 2);

#undef BAR
#undef WLGKM
#undef WVM

#pragma unroll
  for (int m = 0; m < 8; ++m) {
#pragma unroll
    for (int n = 0; n < 4; ++n) {
      long c = col0 + wn * 64 + n * 16 + rl;
      float bv = bias[c];
#pragma unroll
      for (int r = 0; r < 4; ++r) {
        long rr = row0 + wm * 128 + m * 16 + g * 4 + r;
        float v = acc[m][n][r] + bv;
        if (F16OUT) ((f16*)Cout)[rr * NCOLS + c] = (f16)v;
        else        ((float*)Cout)[rr * NCOLS + c] = v;
      }
    }
  }
}

// ======= 128x128 GEMM, BK=128 (R13): amortize the ~1470cy/tile fixed overhead =======
// 10 K-tiles instead of 20; per-tile MFMA work 2x (2484cy) vs same barrier/staging
// overhead. LDS 64KB single-buffered -> 2 blocks/CU (unchanged from BK=64 config).
// Rows now 256B (16 chunks); swizzle phys = chunk ^ (row&7) still bijective and
// bank-spread (phys*4 mod 32 covers all banks over rows 0..7; rows 8..15 2-way=free).
template<int NCOLS>
__global__ __launch_bounds__(256, 2)
void gemm_nt128k(const f16* __restrict__ A, const f16* __restrict__ Bt,
                 const float* __restrict__ bias, float* __restrict__ Cout)
{
  __shared__ __align__(16) char lds[65536];
  char* const sA = lds;
  char* const sB = lds + 32768;
  const int tid = threadIdx.x;
  const int wave = tid >> 6, lane = tid & 63;
  constexpr int NBN = NCOLS / 128;
  const int bm = blockIdx.x / NBN, bn = blockIdx.x % NBN;
  const long row0 = (long)bm * 128, col0 = (long)bn * 128;

  f32x4 acc[4][4];
#pragma unroll
  for (int i = 0; i < 4; ++i)
#pragma unroll
    for (int j = 0; j < 4; ++j) acc[i][j] = (f32x4){0.f, 0.f, 0.f, 0.f};

  const int wr = (wave >> 1) * 64, wc = (wave & 1) * 64;

  // staging: per wave 8 segments of 1KB per matrix per tile (32KB tile = [128][256B]).
  // seg s: o = (wave*8+s)*1024 + lane*16 ; row = o>>8 ; cb = o&255 ;
  // source col pre-swizzled: scb = cb ^ ((row&7)<<4). 16 lanes = exactly one row.
  int segr[8], segoff[8];
#pragma unroll
  for (int i = 0; i < 8; ++i) {
    int o = (wave * 8 + i) * 1024 + lane * 16;
    int r = o >> 8, cb = o & 255;
    segr[i] = r;
    segoff[i] = cb ^ ((r & 7) << 4);
  }

  const char* Ab = (const char*)A;
  const char* Bb = (const char*)Bt;

  for (int kt = 0; kt < 10; ++kt) {
    __syncthreads();   // previous compute done before overwrite
#pragma unroll
    for (int i = 0; i < 8; ++i) {
      const char* ga = Ab + ((row0 + segr[i]) * 1280 + kt * 128) * 2 + segoff[i];
      gload_lds16(ga, sA + (wave * 8 + i) * 1024);
      const char* gb = Bb + ((col0 + segr[i]) * 1280 + kt * 128) * 2 + segoff[i];
      gload_lds16(gb, sB + (wave * 8 + i) * 1024);
    }
    __syncthreads();   // drains vmcnt: tile ready

#pragma unroll
    for (int kk = 0; kk < 4; ++kk) {
      const int rl = lane & 15, g = lane >> 4, x7 = lane & 7;
      const int ph = ((kk * 4 + g) ^ x7) << 4;
      f16x8 af[4], bf[4];
#pragma unroll
      for (int mt = 0; mt < 4; ++mt)
        af[mt] = *(const f16x8*)(sA + (wr + mt * 16 + rl) * 256 + ph);
#pragma unroll
      for (int nt = 0; nt < 4; ++nt)
        bf[nt] = *(const f16x8*)(sB + (wc + nt * 16 + rl) * 256 + ph);
      __builtin_amdgcn_s_setprio(1);
#pragma unroll
      for (int mt = 0; mt < 4; ++mt)
#pragma unroll
        for (int nt = 0; nt < 4; ++nt)
          acc[mt][nt] = __builtin_amdgcn_mfma_f32_16x16x32_f16(af[mt], bf[nt], acc[mt][nt], 0, 0, 0);
      __builtin_amdgcn_s_setprio(0);
    }
  }

  // R6-proven scalar f32 epilogue
  const int rl = lane & 15, g = lane >> 4;
#pragma unroll
  for (int mt = 0; mt < 4; ++mt) {
#pragma unroll
    for (int nt = 0; nt < 4; ++nt) {
      long c = col0 + wc + nt * 16 + rl;
      float bv = bias[c];
#pragma unroll
      for (int r = 0; r < 4; ++r) {
        long rr = row0 + wr + mt * 16 + g * 4 + r;
        Cout[rr * NCOLS + c] = acc[mt][nt][r] + bv;
      }
    }
  }
}

// ---------------- V transpose: qkv v-part -> vt[b*16+h][80][2048] ----------------
__global__ void k_vt(const f16* __restrict__ qkv, f16* __restrict__ vt) {
  __shared__ __align__(16) f16 T[128 * 136];
  int bid = blockIdx.x;              // 64 bh * 16 s-chunks
  int sc16 = bid & 15, bh = bid >> 4;
  int b = bh >> 4, h = bh & 15;
  int s0 = sc16 * 128;
  int t = threadIdx.x;
#pragma unroll
  for (int i = 0; i < 5; ++i) {
    int cid = i * 256 + t;           // 1280 = 128 s * 10 chunks
    int s = cid / 10, c = cid % 10;
    const f16* g = qkv + (size_t)((s0 + s) * 4 + b) * 3840 + 2560 + h * 80 + c * 8;
    f16x8 v = *(const f16x8*)g;
    int phys = c ^ ((s >> 3) & 7);
    *(f16x8*)(T + s * 136 + phys * 8) = v;
  }
  __syncthreads();
#pragma unroll
  for (int i = 0; i < 5; ++i) {
    int oid = i * 256 + t;           // 1280 = 80 hd * 16 s-subchunks
    int sc8 = oid & 15, hd = oid >> 4;
    f16x8 o;
#pragma unroll
    for (int j = 0; j < 8; ++j) {
      int row = sc8 * 8 + j;
      int phys = (hd >> 3) ^ (sc8 & 7);
      o[j] = T[row * 136 + phys * 8 + (hd & 7)];
    }
    *(f16x8*)(vt + (size_t)(bh * 80 + hd) * 2048 + s0 + sc8 * 8) = o;
  }
}

// ---------------- windowed attention (qc-merged) ----------------
__global__ __launch_bounds__(512, 2)
void k_attn(const f16* __restrict__ qkv, const f16* __restrict__ vt,
            f16* __restrict__ ctx)
{
  __shared__ __align__(16) f16 sK[256 * 104];
  __shared__ __align__(16) f16 sV[80 * 264];
  __shared__ __align__(16) f16 sP[256 * 72];

  const int bid = blockIdx.x;                   // 512
  const int seg = bid & 7, h = (bid >> 3) & 15, b = bid >> 7;
  const int t = threadIdx.x;
  const int wave = t >> 6, lane = t & 63;
  const int s_key0 = seg * 256;

#pragma unroll
  for (int i = 0; i < 5; ++i) {
    int cid = i * 512 + t;
    int key = cid / 10, c = cid % 10;
    const f16* g = qkv + (size_t)((s_key0 + key) * 4 + b) * 3840 + 1280 + h * 80 + c * 8;
    *(f16x8*)(sK + key * 104 + c * 8) = *(const f16x8*)g;
  }
  {
    int key = t >> 1, c = t & 1;
    *(f16x8*)(sK + key * 104 + 80 + c * 8) = zero8();
  }
#pragma unroll
  for (int i = 0; i < 5; ++i) {
    int cid = i * 512 + t;
    int hd = cid >> 5, c = cid & 31;
    const f16* g = vt + (size_t)((b * 16 + h) * 80 + hd) * 2048 + s_key0 + c * 8;
    *(f16x8*)(sV + hd * 264 + c * 8) = *(const f16x8*)g;
  }

  const int q0 = s_key0 + wave * 32;
  const int rl = lane & 15, g = lane >> 4;
  f16x8 qfl[3], qfh[3];
  {
    const f16* gl = qkv + (size_t)((q0 + rl) * 4 + b) * 3840 + h * 80;
    const f16* gh = qkv + (size_t)((q0 + 16 + rl) * 4 + b) * 3840 + h * 80;
    qfl[0] = *(const f16x8*)(gl + g * 8);
    qfh[0] = *(const f16x8*)(gh + g * 8);
    qfl[1] = *(const f16x8*)(gl + 32 + g * 8);
    qfh[1] = *(const f16x8*)(gh + 32 + g * 8);
    if (g < 2) { qfl[2] = *(const f16x8*)(gl + 64 + g * 8); qfh[2] = *(const f16x8*)(gh + 64 + g * 8); }
    else       { qfl[2] = zero8(); qfh[2] = zero8(); }
  }
  __syncthreads();

  f32x4 scl[16], sch[16];
#pragma unroll
  for (int nt = 0; nt < 16; ++nt) { scl[nt] = (f32x4){0.f,0.f,0.f,0.f}; sch[nt] = (f32x4){0.f,0.f,0.f,0.f}; }
#pragma unroll
  for (int nt = 0; nt < 16; ++nt) {
#pragma unroll
    for (int kk = 0; kk < 3; ++kk) {
      f16x8 bf = *(const f16x8*)(sK + (nt * 16 + rl) * 104 + kk * 32 + g * 8);
      scl[nt] = __builtin_amdgcn_mfma_f32_16x16x32_f16(qfl[kk], bf, scl[nt], 0, 0, 0);
      sch[nt] = __builtin_amdgcn_mfma_f32_16x16x32_f16(qfh[kk], bf, sch[nt], 0, 0, 0);
    }
  }

  const float scale = 0.11180339887498949f;
  float invl[4], invh[4];
#pragma unroll
  for (int r = 0; r < 4; ++r) {
    float ml = -1e30f, mh = -1e30f;
#pragma unroll
    for (int nt = 0; nt < 16; ++nt) { ml = fmaxf(ml, scl[nt][r]); mh = fmaxf(mh, sch[nt][r]); }
#pragma unroll
    for (int off = 8; off >= 1; off >>= 1) { ml = fmaxf(ml, __shfl_xor(ml, off)); mh = fmaxf(mh, __shfl_xor(mh, off)); }
    ml *= scale; mh *= scale;
    float suml = 0.f, sumh = 0.f;
#pragma unroll
    for (int nt = 0; nt < 16; ++nt) {
      float pl = __expf(scl[nt][r] * scale - ml);
      float ph = __expf(sch[nt][r] * scale - mh);
      scl[nt][r] = pl; sch[nt][r] = ph;
      suml += pl; sumh += ph;
    }
#pragma unroll
    for (int off = 8; off >= 1; off >>= 1) { suml += __shfl_xor(suml, off); sumh += __shfl_xor(sumh, off); }
    invl[r] = 1.0f / suml; invh[r] = 1.0f / sumh;
  }

  f32x4 ol[5], oh[5];
#pragma unroll
  for (int nt = 0; nt < 5; ++nt) { ol[nt] = (f32x4){0.f,0.f,0.f,0.f}; oh[nt] = (f32x4){0.f,0.f,0.f,0.f}; }
  const int prow0 = wave * 32;
  for (int ch = 0; ch < 4; ++ch) {
#pragma unroll
    for (int f = 0; f < 4; ++f) {
      int nt = ch * 4 + f;
#pragma unroll
      for (int r = 0; r < 4; ++r) {
        sP[(prow0 + g * 4 + r) * 72 + f * 16 + rl]      = (f16)scl[nt][r];
        sP[(prow0 + 16 + g * 4 + r) * 72 + f * 16 + rl] = (f16)sch[nt][r];
      }
    }
#pragma unroll
    for (int kk = 0; kk < 2; ++kk) {
      f16x8 pal = *(const f16x8*)(sP + (prow0 + rl) * 72 + kk * 32 + g * 8);
      f16x8 pah = *(const f16x8*)(sP + (prow0 + 16 + rl) * 72 + kk * 32 + g * 8);
#pragma unroll
      for (int nt = 0; nt < 5; ++nt) {
        f16x8 vb = *(const f16x8*)(sV + (nt * 16 + rl) * 264 + ch * 64 + kk * 32 + g * 8);
        ol[nt] = __builtin_amdgcn_mfma_f32_16x16x32_f16(pal, vb, ol[nt], 0, 0, 0);
        oh[nt] = __builtin_amdgcn_mfma_f32_16x16x32_f16(pah, vb, oh[nt], 0, 0, 0);
      }
    }
  }

#pragma unroll
  for (int nt = 0; nt < 5; ++nt) {
    int hd = nt * 16 + rl;
#pragma unroll
    for (int r = 0; r < 4; ++r) {
      long qrl = q0 + g * 4 + r;
      ctx[(qrl * 4 + b) * 1280 + h * 80 + hd] = (f16)(ol[nt][r] * invl[r]);
      long qrh = q0 + 16 + g * 4 + r;
      ctx[(qrh * 4 + b) * 1280 + h * 80 + hd] = (f16)(oh[nt][r] * invh[r]);
    }
  }
}

extern "C" void kernel_launch(void* const* d_in, const int* in_sizes, int n_in,
                              void* d_out, int out_size, void* d_ws, size_t ws_size,
                              hipStream_t stream)
{
  const float* x     = (const float*)d_in[0];
  const float* Wqkv  = (const float*)d_in[1];
  const float* bqkv  = (const float*)d_in[2];
  const float* Wproj = (const float*)d_in[3];
  const float* bproj = (const float*)d_in[4];

  char* ws = (char*)d_ws;
  f16* X16   = (f16*)(ws);                 // 20,971,520 B (reused as CTX16 after gemm1)
  f16* WQT   = (f16*)(ws + 20971520);      //  9,830,400 B
  f16* WPT   = (f16*)(ws + 30801920);      // 13,107,200 B
  f16* QKV16 = (f16*)(ws + 43909120);      // 62,914,560 B
  f16* VT    = (f16*)(ws + 106823680);     // 20,971,520 B  (total 127,795,200 B)
  f16* CTX16 = X16;                        // x dead after gemm1

  k_prep<<<13248, 256, 0, stream>>>(x, Wqkv, Wproj, X16, WQT, WPT);
  gemm_nt256<3840, true><<<480, 512, 0, stream>>>(X16, WQT, bqkv, QKV16);   // 97.7us measured
  k_vt<<<1024, 256, 0, stream>>>(QKV16, VT);
  k_attn<<<512, 512, 0, stream>>>(QKV16, VT, CTX16);
  gemm_nt128k<5120><<<64 * 40, 256, 0, stream>>>(CTX16, WPT, bproj, (float*)d_out);
}

// Round 14
// 244.441 us; speedup vs baseline: 1.1519x; 1.0766x over previous
//
#include <hip/hip_runtime.h>

typedef _Float16 f16;
typedef _Float16 f16x8 __attribute__((ext_vector_type(8)));
typedef _Float16 f16x4 __attribute__((ext_vector_type(4)));
typedef float    f32x4 __attribute__((ext_vector_type(4)));
typedef unsigned int u32t;

#define AS1 __attribute__((address_space(1)))
#define AS3 __attribute__((address_space(3)))

static __device__ __forceinline__ void gload_lds16(const void* g, void* l) {
  __builtin_amdgcn_global_load_lds((const AS1 u32t*)g, (AS3 u32t*)l, 16, 0, 0);
}

static __device__ __forceinline__ f16x8 zero8() {
  f16x8 z;
#pragma unroll
  for (int j = 0; j < 8; ++j) z[j] = (f16)0;
  return z;
}

// ------------- fused prep: W transposes + x convert in ONE launch -------------
__global__ void k_prep(const float* __restrict__ x,
                       const float* __restrict__ Wqkv,
                       const float* __restrict__ Wproj,
                       f16* __restrict__ X16, f16* __restrict__ WQT,
                       f16* __restrict__ WPT)
{
  __shared__ float T[32][33];
  const int bid = blockIdx.x;
  if (bid < 11200) {
    const float* W; f16* Wt; int N; int b2;
    if (bid < 4800) { W = Wqkv;  Wt = WQT; N = 3840; b2 = bid; }
    else            { W = Wproj; Wt = WPT; N = 5120; b2 = bid - 4800; }
    int bk = b2 % 40, bn = b2 / 40;
    int k0 = bk * 32, n0 = bn * 32;
    int r = threadIdx.x >> 5, c = threadIdx.x & 31;
#pragma unroll
    for (int i = 0; i < 4; ++i)
      T[r + i * 8][c] = W[(size_t)(k0 + r + i * 8) * N + n0 + c];
    __syncthreads();
#pragma unroll
    for (int i = 0; i < 4; ++i)
      Wt[(size_t)(n0 + r + i * 8) * 1280 + k0 + c] = (f16)T[c][r + i * 8];
  } else {
    const int n4 = 8192 * 1280 / 4;
    for (int i = (bid - 11200) * 256 + threadIdx.x; i < n4; i += 2048 * 256) {
      float4 v = ((const float4*)x)[i];
      f16x4 o;
      o[0] = (f16)v.x; o[1] = (f16)v.y; o[2] = (f16)v.z; o[3] = (f16)v.w;
      ((f16x4*)X16)[i] = o;
    }
  }
}

// ======= 256x256 GEMM, BK=64, 4-phase/tile counted-vmcnt (gemm1: 97.7us MEASURED) =======
template<int NCOLS, bool F16OUT>
__global__ __launch_bounds__(512, 1)
void gemm_nt256(const f16* __restrict__ A, const f16* __restrict__ Bt,
                const float* __restrict__ bias, void* __restrict__ Cout)
{
  __shared__ __align__(16) char lds[131072];
  const int tid = threadIdx.x;
  const int wave = tid >> 6, lane = tid & 63;
  const int rl = lane & 15, g = lane >> 4;
  const int wm = wave >> 2, wn = wave & 3;

  constexpr int NBN = NCOLS / 256;
  constexpr int NWG = 32 * NBN;
  const int bid = blockIdx.x;
  const int wgid = (bid & 7) * (NWG / 8) + (bid >> 3);   // XCD swizzle (NWG%8==0)
  const int bm = wgid / NBN, bn = wgid % NBN;
  const long row0 = (long)bm * 256, col0 = (long)bn * 256;

  const int subA = wave * 8 + (lane >> 3);                    // 0..63
  const int cpA  = (((lane & 7) ^ (subA & 7)) << 4);
  const char* gAt = (const char*)A + (row0 + subA) * 2560 + cpA;
  const int subB = (wave & 3) * 8 + (lane >> 3);              // 0..31
  const int cpB  = (((lane & 7) ^ (subB & 7)) << 4);
  const char* gBt = (const char*)Bt + (col0 + (wave >> 2) * 64 + subB) * 2560 + cpB;
  char* const dA = lds + wave * 1024;
  char* const dB = lds + 65536 + wave * 1024;

  auto STA = [&](int mh, int buf, int kb) {
#pragma unroll
    for (int l = 0; l < 2; ++l)
      gload_lds16(gAt + mh * (64 * 2560) + l * (128 * 2560) + kb,
                  dA + buf * 32768 + mh * 16384 + l * 8192);
  };
  auto STB = [&](int nh, int buf, int kb) {
#pragma unroll
    for (int l = 0; l < 2; ++l)
      gload_lds16(gBt + nh * (32 * 2560) + l * (128 * 2560) + kb,
                  dB + buf * 32768 + nh * 16384 + l * 8192);
  };

  const int swz0 = ((0 + g) ^ (rl & 7)) << 4;
  const int swz1 = ((4 + g) ^ (rl & 7)) << 4;
  const int aro = wm * 8192 + rl * 128;
  const int bro = 65536 + wn * 4096 + rl * 128;

  auto LDA = [&](f16x8 (&af)[8], int buf, int mh) {
#pragma unroll
    for (int m = 0; m < 4; ++m) {
      const char* p = lds + buf * 32768 + mh * 16384 + aro + m * 2048;
      af[m * 2 + 0] = *(const f16x8*)(p + swz0);
      af[m * 2 + 1] = *(const f16x8*)(p + swz1);
    }
  };
  auto LDB = [&](f16x8 (&bf)[4], int buf, int nh) {
#pragma unroll
    for (int n = 0; n < 2; ++n) {
      const char* p = lds + buf * 32768 + nh * 16384 + bro + n * 2048;
      bf[n * 2 + 0] = *(const f16x8*)(p + swz0);
      bf[n * 2 + 1] = *(const f16x8*)(p + swz1);
    }
  };

  f32x4 acc[8][4];
#pragma unroll
  for (int m = 0; m < 8; ++m)
#pragma unroll
    for (int n = 0; n < 4; ++n) acc[m][n] = (f32x4){0.f, 0.f, 0.f, 0.f};

  auto MM = [&](int mh, int nh, const f16x8 (&af)[8], const f16x8 (&bf)[4]) {
    __builtin_amdgcn_s_setprio(1);
#pragma unroll
    for (int m = 0; m < 4; ++m)
#pragma unroll
      for (int n = 0; n < 2; ++n)
#pragma unroll
        for (int kk = 0; kk < 2; ++kk)
          acc[mh * 4 + m][nh * 2 + n] = __builtin_amdgcn_mfma_f32_16x16x32_f16(
              af[m * 2 + kk], bf[n * 2 + kk], acc[mh * 4 + m][nh * 2 + n], 0, 0, 0);
    __builtin_amdgcn_s_setprio(0);
  };

#define BAR()   do { __builtin_amdgcn_s_barrier(); asm volatile("" ::: "memory"); } while (0)
#define WLGKM() asm volatile("s_waitcnt lgkmcnt(0)" ::: "memory")
#define WVM(N)  asm volatile("s_waitcnt vmcnt(" #N ")" ::: "memory")

  auto TILE = [&](int buf, int kbB1, int kbN, int mode) {
    f16x8 af[8], bf0[4], bf1[4];
    LDA(af, buf, 0); LDB(bf0, buf, 0);
    if (mode <= 1) STB(1, buf ^ 1, kbB1);
    BAR(); WLGKM(); MM(0, 0, af, bf0); BAR();
    LDB(bf1, buf, 1);
    if (mode == 0) STA(0, buf, kbN);
    BAR(); WLGKM(); MM(0, 1, af, bf1); BAR();
    LDA(af, buf, 1);
    if (mode == 0) STB(0, buf, kbN);
    BAR(); WLGKM(); MM(1, 1, af, bf1); BAR();
    if (mode == 0) STA(1, buf, kbN);
    if (mode == 0) { WVM(6); } else if (mode == 1) { WVM(0); }
    BAR(); MM(1, 0, af, bf0);
    if (mode != 2) BAR();
  };

  STA(0, 0, 0); STB(0, 0, 0); STA(1, 0, 0); STB(1, 0, 0);
  STA(0, 1, 128); STB(0, 1, 128); STA(1, 1, 128);
  WVM(6); BAR();

#pragma unroll 1
  for (int it = 0; it < 9; ++it) {
    const int kb = it * 256;
    TILE(0, kb + 128, kb + 256, 0);
    TILE(1, kb + 256, kb + 384, 0);
  }
  TILE(0, 2432, 0, 1);
  TILE(1, 0, 0, 2);

#undef BAR
#undef WLGKM
#undef WVM

#pragma unroll
  for (int m = 0; m < 8; ++m) {
#pragma unroll
    for (int n = 0; n < 4; ++n) {
      long c = col0 + wn * 64 + n * 16 + rl;
      float bv = bias[c];
#pragma unroll
      for (int r = 0; r < 4; ++r) {
        long rr = row0 + wm * 128 + m * 16 + g * 4 + r;
        float v = acc[m][n][r] + bv;
        if (F16OUT) ((f16*)Cout)[rr * NCOLS + c] = (f16)v;
        else        ((float*)Cout)[rr * NCOLS + c] = v;
      }
    }
  }
}

// ======= 128x128 GEMM, BK=64 (R11-exact: 113.4us measured, 0 conflicts) =======
template<int NCOLS>
__global__ __launch_bounds__(256, 4)
void gemm_nt128(const f16* __restrict__ A, const f16* __restrict__ Bt,
                const float* __restrict__ bias, float* __restrict__ Cout)
{
  __shared__ __align__(16) char lds[32768];
  f16* const sA = (f16*)lds;
  f16* const sB = (f16*)(lds + 16384);
  const int tid = threadIdx.x;
  const int wave = tid >> 6, lane = tid & 63;
  constexpr int NBN = NCOLS / 128;
  const int bm = blockIdx.x / NBN, bn = blockIdx.x % NBN;
  const long row0 = (long)bm * 128, col0 = (long)bn * 128;

  f32x4 acc[4][4];
#pragma unroll
  for (int i = 0; i < 4; ++i)
#pragma unroll
    for (int j = 0; j < 4; ++j) acc[i][j] = (f32x4){0.f, 0.f, 0.f, 0.f};

  const int wr = (wave >> 1) * 64, wc = (wave & 1) * 64;

  int segr[4], segoff[4];
#pragma unroll
  for (int i = 0; i < 4; ++i) {
    int o = (wave * 4 + i) * 1024 + lane * 16;
    int r = o >> 7, cb = o & 127;
    segr[i] = r;
    segoff[i] = cb ^ ((r & 7) << 4);
  }

  const char* Ab = (const char*)A;
  const char* Bb = (const char*)Bt;

  for (int kt = 0; kt < 20; ++kt) {
    __syncthreads();
#pragma unroll
    for (int i = 0; i < 4; ++i) {
      const char* ga = Ab + ((row0 + segr[i]) * 1280 + kt * 64) * 2 + segoff[i];
      gload_lds16(ga, (char*)sA + (wave * 4 + i) * 1024);
      const char* gb = Bb + ((col0 + segr[i]) * 1280 + kt * 64) * 2 + segoff[i];
      gload_lds16(gb, (char*)sB + (wave * 4 + i) * 1024);
    }
    __syncthreads();

#pragma unroll
    for (int kk = 0; kk < 2; ++kk) {
      const int rl = lane & 15, g = lane >> 4, x7 = lane & 7;
      const int ph = (kk * 4 + g) ^ x7;
      f16x8 af[4], bf[4];
#pragma unroll
      for (int mt = 0; mt < 4; ++mt)
        af[mt] = *(const f16x8*)(sA + (wr + mt * 16 + rl) * 64 + ph * 8);
#pragma unroll
      for (int nt = 0; nt < 4; ++nt)
        bf[nt] = *(const f16x8*)(sB + (wc + nt * 16 + rl) * 64 + ph * 8);
#pragma unroll
      for (int mt = 0; mt < 4; ++mt)
#pragma unroll
        for (int nt = 0; nt < 4; ++nt)
          acc[mt][nt] = __builtin_amdgcn_mfma_f32_16x16x32_f16(af[mt], bf[nt], acc[mt][nt], 0, 0, 0);
    }
  }

  const int rl = lane & 15, g = lane >> 4;
#pragma unroll
  for (int mt = 0; mt < 4; ++mt) {
#pragma unroll
    for (int nt = 0; nt < 4; ++nt) {
      long c = col0 + wc + nt * 16 + rl;
      float bv = bias[c];
#pragma unroll
      for (int r = 0; r < 4; ++r) {
        long rr = row0 + wr + mt * 16 + g * 4 + r;
        Cout[rr * NCOLS + c] = acc[mt][nt][r] + bv;
      }
    }
  }
}

// ---------------- windowed attention (qc-merged, V-transpose FUSED) ----------------
// block: (b, h, seg) = 512 blocks; 512 threads = 8 waves * 32 queries.
// R14: k_vt eliminated. V staged directly from QKV16 [key][hd] into transposed
// swizzled sV[80][256]: phys_chunk = chunk ^ ((hd ^ (hd>>3)) & 7).
//  - write side: lanes share key, vary hd-octet (hd>>3 varies) -> 8 distinct banks
//  - read side: lanes vary rl -> hd&7 varies -> >=8 distinct chunks, <=2-way (free)
// Same formula both sides; XOR on chunk bits -> bijective per row.
__global__ __launch_bounds__(512, 2)
void k_attn(const f16* __restrict__ qkv, f16* __restrict__ ctx)
{
  __shared__ __align__(16) f16 sK[256 * 104];   // keys x (80 + zero-pad to 96, stride 104)
  __shared__ __align__(16) f16 sV[80 * 256];    // hd x 256 keys, swizzled (40KB)
  __shared__ __align__(16) f16 sP[256 * 72];    // q x 64-key chunk (stride 72)

  const int bid = blockIdx.x;                   // 512
  const int seg = bid & 7, h = (bid >> 3) & 15, b = bid >> 7;
  const int t = threadIdx.x;
  const int wave = t >> 6, lane = t & 63;
  const int s_key0 = seg * 256;

  // stage K (k-part of qkv, col base 1280 + h*80)
#pragma unroll
  for (int i = 0; i < 5; ++i) {
    int cid = i * 512 + t;                      // 2560 = 256 keys * 10 chunks
    int key = cid / 10, c = cid % 10;
    const f16* g = qkv + (size_t)((s_key0 + key) * 4 + b) * 3840 + 1280 + h * 80 + c * 8;
    *(f16x8*)(sK + key * 104 + c * 8) = *(const f16x8*)g;
  }
  { // zero cols 80..95
    int key = t >> 1, c = t & 1;
    *(f16x8*)(sK + key * 104 + 80 + c * 8) = zero8();
  }
  // stage V TRANSPOSED from qkv v-part (col base 2560 + h*80): read [key][hd-octet],
  // scatter 8 scalars into swizzled sV[hd][key].
#pragma unroll
  for (int i = 0; i < 5; ++i) {
    int cid = i * 512 + t;                      // 2560 = 256 keys * 10 octets
    int key = cid / 10, c = cid % 10;
    const f16* g = qkv + (size_t)((s_key0 + key) * 4 + b) * 3840 + 2560 + h * 80 + c * 8;
    f16x8 v = *(const f16x8*)g;
    const int kc = key >> 3, kl = key & 7;
#pragma unroll
    for (int j = 0; j < 8; ++j) {
      int hd = c * 8 + j;
      int pc = kc ^ ((hd ^ (hd >> 3)) & 7);
      sV[hd * 256 + pc * 8 + kl] = v[j];
    }
  }

  // Q fragments direct from global; wave owns 32 queries (lo: +rl, hi: +16+rl)
  const int q0 = s_key0 + wave * 32;
  const int rl = lane & 15, g = lane >> 4;
  f16x8 qfl[3], qfh[3];
  {
    const f16* gl = qkv + (size_t)((q0 + rl) * 4 + b) * 3840 + h * 80;
    const f16* gh = qkv + (size_t)((q0 + 16 + rl) * 4 + b) * 3840 + h * 80;
    qfl[0] = *(const f16x8*)(gl + g * 8);
    qfh[0] = *(const f16x8*)(gh + g * 8);
    qfl[1] = *(const f16x8*)(gl + 32 + g * 8);
    qfh[1] = *(const f16x8*)(gh + 32 + g * 8);
    if (g < 2) { qfl[2] = *(const f16x8*)(gl + 64 + g * 8); qfh[2] = *(const f16x8*)(gh + 64 + g * 8); }
    else       { qfl[2] = zero8(); qfh[2] = zero8(); }
  }
  __syncthreads();

  // QK^T
  f32x4 scl[16], sch[16];
#pragma unroll
  for (int nt = 0; nt < 16; ++nt) { scl[nt] = (f32x4){0.f,0.f,0.f,0.f}; sch[nt] = (f32x4){0.f,0.f,0.f,0.f}; }
#pragma unroll
  for (int nt = 0; nt < 16; ++nt) {
#pragma unroll
    for (int kk = 0; kk < 3; ++kk) {
      f16x8 bf = *(const f16x8*)(sK + (nt * 16 + rl) * 104 + kk * 32 + g * 8);
      scl[nt] = __builtin_amdgcn_mfma_f32_16x16x32_f16(qfl[kk], bf, scl[nt], 0, 0, 0);
      sch[nt] = __builtin_amdgcn_mfma_f32_16x16x32_f16(qfh[kk], bf, sch[nt], 0, 0, 0);
    }
  }

  // softmax (exact, full 256-key window in regs) for both halves
  const float scale = 0.11180339887498949f;
  float invl[4], invh[4];
#pragma unroll
  for (int r = 0; r < 4; ++r) {
    float ml = -1e30f, mh = -1e30f;
#pragma unroll
    for (int nt = 0; nt < 16; ++nt) { ml = fmaxf(ml, scl[nt][r]); mh = fmaxf(mh, sch[nt][r]); }
#pragma unroll
    for (int off = 8; off >= 1; off >>= 1) { ml = fmaxf(ml, __shfl_xor(ml, off)); mh = fmaxf(mh, __shfl_xor(mh, off)); }
    ml *= scale; mh *= scale;
    float suml = 0.f, sumh = 0.f;
#pragma unroll
    for (int nt = 0; nt < 16; ++nt) {
      float pl = __expf(scl[nt][r] * scale - ml);
      float ph = __expf(sch[nt][r] * scale - mh);
      scl[nt][r] = pl; sch[nt][r] = ph;
      suml += pl; sumh += ph;
    }
#pragma unroll
    for (int off = 8; off >= 1; off >>= 1) { suml += __shfl_xor(suml, off); sumh += __shfl_xor(sumh, off); }
    invl[r] = 1.0f / suml; invh[r] = 1.0f / sumh;
  }

  // PV: vb read from swizzled sV
  f32x4 ol[5], oh[5];
#pragma unroll
  for (int nt = 0; nt < 5; ++nt) { ol[nt] = (f32x4){0.f,0.f,0.f,0.f}; oh[nt] = (f32x4){0.f,0.f,0.f,0.f}; }
  const int prow0 = wave * 32;
  for (int ch = 0; ch < 4; ++ch) {
#pragma unroll
    for (int f = 0; f < 4; ++f) {
      int nt = ch * 4 + f;
#pragma unroll
      for (int r = 0; r < 4; ++r) {
        sP[(prow0 + g * 4 + r) * 72 + f * 16 + rl]      = (f16)scl[nt][r];
        sP[(prow0 + 16 + g * 4 + r) * 72 + f * 16 + rl] = (f16)sch[nt][r];
      }
    }
#pragma unroll
    for (int kk = 0; kk < 2; ++kk) {
      f16x8 pal = *(const f16x8*)(sP + (prow0 + rl) * 72 + kk * 32 + g * 8);
      f16x8 pah = *(const f16x8*)(sP + (prow0 + 16 + rl) * 72 + kk * 32 + g * 8);
#pragma unroll
      for (int nt = 0; nt < 5; ++nt) {
        int hd = nt * 16 + rl;
        int pc = (ch * 8 + kk * 4 + g) ^ ((hd ^ (hd >> 3)) & 7);
        f16x8 vb = *(const f16x8*)(sV + hd * 256 + pc * 8);
        ol[nt] = __builtin_amdgcn_mfma_f32_16x16x32_f16(pal, vb, ol[nt], 0, 0, 0);
        oh[nt] = __builtin_amdgcn_mfma_f32_16x16x32_f16(pah, vb, oh[nt], 0, 0, 0);
      }
    }
  }

  // epilogue: normalize, store ctx fp16 (both halves)
#pragma unroll
  for (int nt = 0; nt < 5; ++nt) {
    int hd = nt * 16 + rl;
#pragma unroll
    for (int r = 0; r < 4; ++r) {
      long qrl = q0 + g * 4 + r;
      ctx[(qrl * 4 + b) * 1280 + h * 80 + hd] = (f16)(ol[nt][r] * invl[r]);
      long qrh = q0 + 16 + g * 4 + r;
      ctx[(qrh * 4 + b) * 1280 + h * 80 + hd] = (f16)(oh[nt][r] * invh[r]);
    }
  }
}

extern "C" void kernel_launch(void* const* d_in, const int* in_sizes, int n_in,
                              void* d_out, int out_size, void* d_ws, size_t ws_size,
                              hipStream_t stream)
{
  const float* x     = (const float*)d_in[0];
  const float* Wqkv  = (const float*)d_in[1];
  const float* bqkv  = (const float*)d_in[2];
  const float* Wproj = (const float*)d_in[3];
  const float* bproj = (const float*)d_in[4];

  char* ws = (char*)d_ws;
  f16* X16   = (f16*)(ws);                 // 20,971,520 B (reused as CTX16 after gemm1)
  f16* WQT   = (f16*)(ws + 20971520);      //  9,830,400 B
  f16* WPT   = (f16*)(ws + 30801920);      // 13,107,200 B
  f16* QKV16 = (f16*)(ws + 43909120);      // 62,914,560 B
  f16* CTX16 = X16;                        // x dead after gemm1

  k_prep<<<13248, 256, 0, stream>>>(x, Wqkv, Wproj, X16, WQT, WPT);
  gemm_nt256<3840, true><<<480, 512, 0, stream>>>(X16, WQT, bqkv, QKV16);   // 97.7us measured
  k_attn<<<512, 512, 0, stream>>>(QKV16, CTX16);                            // V-transpose fused
  gemm_nt128<5120><<<64 * 40, 256, 0, stream>>>(CTX16, WPT, bproj, (float*)d_out); // 113.4us measured
}